// Round 1
// baseline (350.655 us; speedup 1.0000x reference)
//
#include <hip/hip_runtime.h>
#include <hip/hip_bf16.h>
#include <cstdint>
#include <cstddef>

#define DDIM 1024
#define BROWS 32768

typedef __attribute__((ext_vector_type(8))) short short8;
typedef __attribute__((ext_vector_type(4))) float floatx4;

__device__ __forceinline__ float bf2f(unsigned short u) {
  return __uint_as_float(((unsigned int)u) << 16);
}
__device__ __forceinline__ unsigned short f2bf(float f) {
  unsigned int u = __float_as_uint(f);
  u += 0x7FFFu + ((u >> 16) & 1u);
  return (unsigned short)(u >> 16);
}

__device__ __forceinline__ void load_lds16(const void* g, void* l) {
  __builtin_amdgcn_global_load_lds(
      (const __attribute__((address_space(1))) unsigned int*)g,
      (__attribute__((address_space(3))) unsigned int*)l,
      16, 0, 0);
}

// C[i][j] = sum_k A[i][k] * Bt[j][k]   (GEMM with B stored transposed)
// A_BF16: A is bf16 (global_load_lds) else f32 (reg-stage + convert)
// EPI==0: out bf16 with scale c^2 (c from in_max) + atomicMax |out| -> out_max
// EPI==1: out f32 = acc*inv + bias[col]
template<int A_BF16, int EPI>
__global__ void __launch_bounds__(256, 2)
gemm_bt(const void* __restrict__ Aptr, const unsigned short* __restrict__ Bt,
        void* __restrict__ Outp,
        const float* __restrict__ in_max, float* __restrict__ out_max,
        const float* __restrict__ inv_ptr, const float* __restrict__ bias)
{
  __shared__ unsigned short As[128 * 32];
  __shared__ unsigned short Bs[128 * 32];
  __shared__ float redbuf[256];

  const int tid  = threadIdx.x;
  const int lane = tid & 63;
  const int wid  = tid >> 6;
  const int wr = wid >> 1, wc = wid & 1;
  const int g = lane >> 4, r = lane & 15;

  const int bn0 = (int)(blockIdx.x & 7) * 128;
  const int bm0 = (int)(blockIdx.x >> 3) * 128;

  const floatx4 zero4 = {0.f, 0.f, 0.f, 0.f};
  floatx4 acc[4][4];
#pragma unroll
  for (int m = 0; m < 4; ++m)
#pragma unroll
    for (int n = 0; n < 4; ++n) acc[m][n] = zero4;

  for (int kk = 0; kk < DDIM; kk += 32) {
    __syncthreads();
    // stage B tile (always bf16)
#pragma unroll
    for (int p = 0; p < 2; ++p) {
      const int o = p * 4096 + tid * 16;       // byte offset in tile
      const int row = o >> 6;                  // 64B per row (32 bf16)
      const int cole = (o & 63) >> 1;          // element col (0,8,16,24)
      load_lds16(Bt + (size_t)(bn0 + row) * DDIM + kk + cole, (char*)Bs + o);
    }
    // stage A tile
    if constexpr (A_BF16) {
      const unsigned short* Ab = (const unsigned short*)Aptr;
#pragma unroll
      for (int p = 0; p < 2; ++p) {
        const int o = p * 4096 + tid * 16;
        const int row = o >> 6;
        const int cole = (o & 63) >> 1;
        load_lds16(Ab + (size_t)(bm0 + row) * DDIM + kk + cole, (char*)As + o);
      }
    } else {
      const float* Af = (const float*)Aptr;
#pragma unroll
      for (int p = 0; p < 2; ++p) {
        const int o = p * 4096 + tid * 16;
        const int row = o >> 6;
        const int cole = (o & 63) >> 1;
        const float4* s = (const float4*)(Af + (size_t)(bm0 + row) * DDIM + kk + cole);
        float4 x0 = s[0], x1 = s[1];
        short8 t;
        t[0] = (short)f2bf(x0.x); t[1] = (short)f2bf(x0.y);
        t[2] = (short)f2bf(x0.z); t[3] = (short)f2bf(x0.w);
        t[4] = (short)f2bf(x1.x); t[5] = (short)f2bf(x1.y);
        t[6] = (short)f2bf(x1.z); t[7] = (short)f2bf(x1.w);
        *(short8*)((char*)As + o) = t;
      }
    }
    __syncthreads();

    short8 afr[4], bfr[4];
#pragma unroll
    for (int m = 0; m < 4; ++m)
      afr[m] = *(const short8*)((const char*)As + (wr * 64 + m * 16 + r) * 64 + g * 16);
#pragma unroll
    for (int n = 0; n < 4; ++n)
      bfr[n] = *(const short8*)((const char*)Bs + (wc * 64 + n * 16 + r) * 64 + g * 16);
#pragma unroll
    for (int m = 0; m < 4; ++m)
#pragma unroll
      for (int n = 0; n < 4; ++n)
        acc[m][n] = __builtin_amdgcn_mfma_f32_16x16x32_bf16(afr[m], bfr[n], acc[m][n], 0, 0, 0);
  }

  if constexpr (EPI == 0) {
    unsigned short* Outb = (unsigned short*)Outp;
    float c = 1.0f;
    if (in_max != nullptr) {
      int e;
      (void)frexpf(*in_max, &e);
      c = ldexpf(1.0f, -e);            // power of two: c*max in [0.5,1)
    }
    const float c2 = c * c;
    float lmax = 0.0f;
#pragma unroll
    for (int m = 0; m < 4; ++m) {
      const int orow0 = bm0 + wr * 64 + m * 16 + g * 4;
#pragma unroll
      for (int n = 0; n < 4; ++n) {
        const int ocol = bn0 + wc * 64 + n * 16 + r;
#pragma unroll
        for (int q = 0; q < 4; ++q) {
          float v = acc[m][n][q] * c2;
          Outb[(size_t)(orow0 + q) * DDIM + ocol] = f2bf(v);
          lmax = fmaxf(lmax, fabsf(v));
        }
      }
    }
    redbuf[tid] = lmax;
    __syncthreads();
    for (int s = 128; s > 0; s >>= 1) {
      if (tid < s) redbuf[tid] = fmaxf(redbuf[tid], redbuf[tid + s]);
      __syncthreads();
    }
    if (tid == 0) atomicMax((unsigned int*)out_max, __float_as_uint(redbuf[0]));
  } else {
    float* Outf = (float*)Outp;
    const float inv = *inv_ptr;
#pragma unroll
    for (int n = 0; n < 4; ++n) {
      const int ocol = bn0 + wc * 64 + n * 16 + r;
      const float bv = bias[ocol];
#pragma unroll
      for (int m = 0; m < 4; ++m) {
        const int orow0 = bm0 + wr * 64 + m * 16 + g * 4;
#pragma unroll
        for (int q = 0; q < 4; ++q) {
          Outf[(size_t)(orow0 + q) * DDIM + ocol] = acc[m][n][q] * inv + bv;
        }
      }
    }
  }
}

// WT[n][k] = bf16(W[k][n])
__global__ void __launch_bounds__(256)
transpose_bf16(const float* __restrict__ W, unsigned short* __restrict__ WT)
{
  __shared__ float tile[64][65];
  const int bx = blockIdx.x & 15;   // k tile
  const int by = blockIdx.x >> 4;   // n tile
  const int tid = threadIdx.x;
  const int c = tid & 63;
  const int r0 = tid >> 6;
#pragma unroll
  for (int p = 0; p < 16; ++p) {
    int kr = p * 4 + r0;
    tile[kr][c] = W[(size_t)(bx * 64 + kr) * DDIM + by * 64 + c];
  }
  __syncthreads();
#pragma unroll
  for (int p = 0; p < 16; ++p) {
    int nr = p * 4 + r0;
    WT[(size_t)(by * 64 + nr) * DDIM + bx * 64 + c] = f2bf(tile[c][nr]);
  }
}

// vout[j] = 2^-12 * sum_i vin[i] * P[j][i]   (P symmetric bf16 1024x1024)
__global__ void __launch_bounds__(256)
gemv_pow(const unsigned short* __restrict__ P, const float* __restrict__ vin,
         float* __restrict__ vout)
{
  const int tid = threadIdx.x;
  const int lane = tid & 63;
  const int wid = tid >> 6;
  float vs[16];
  const float4* vv = (const float4*)(vin + lane * 16);
#pragma unroll
  for (int i = 0; i < 4; ++i) {
    float4 t = vv[i];
    vs[i * 4 + 0] = t.x; vs[i * 4 + 1] = t.y; vs[i * 4 + 2] = t.z; vs[i * 4 + 3] = t.w;
  }
#pragma unroll
  for (int rr = 0; rr < 4; ++rr) {
    const int row = (int)blockIdx.x * 16 + wid * 4 + rr;
    const unsigned short* pr = P + (size_t)row * DDIM + lane * 16;
    short8 p0 = *(const short8*)pr;
    short8 p1 = *(const short8*)(pr + 8);
    float s = 0.f;
#pragma unroll
    for (int e = 0; e < 8; ++e) s += bf2f((unsigned short)p0[e]) * vs[e];
#pragma unroll
    for (int e = 0; e < 8; ++e) s += bf2f((unsigned short)p1[e]) * vs[8 + e];
#pragma unroll
    for (int off = 32; off > 0; off >>= 1) s += __shfl_down(s, off);
    if (lane == 0) vout[row] = s * 0x1p-12f;
  }
}

// v_un[i] = sum_j d[j] * W[i][j]; per-block ssq partial -> vpart[bid]
__global__ void __launch_bounds__(256)
v_kernel(const float* __restrict__ W, const float* __restrict__ d,
         float* __restrict__ v_un, float* __restrict__ vpart)
{
  __shared__ float wsum[4];
  const int tid = threadIdx.x;
  const int lane = tid & 63;
  const int wid = tid >> 6;
  float vs[16];
  const float4* dv = (const float4*)(d + lane * 16);
#pragma unroll
  for (int i = 0; i < 4; ++i) {
    float4 t = dv[i];
    vs[i * 4 + 0] = t.x; vs[i * 4 + 1] = t.y; vs[i * 4 + 2] = t.z; vs[i * 4 + 3] = t.w;
  }
  float ssq = 0.f;
#pragma unroll
  for (int rr = 0; rr < 4; ++rr) {
    const int row = (int)blockIdx.x * 16 + wid * 4 + rr;
    const float4* wrow = (const float4*)(W + (size_t)row * DDIM + lane * 16);
    float s = 0.f;
#pragma unroll
    for (int i = 0; i < 4; ++i) {
      float4 t = wrow[i];
      s += t.x * vs[i * 4 + 0] + t.y * vs[i * 4 + 1] + t.z * vs[i * 4 + 2] + t.w * vs[i * 4 + 3];
    }
#pragma unroll
    for (int off = 32; off > 0; off >>= 1) s += __shfl_down(s, off);
    if (lane == 0) { v_un[row] = s; ssq += s * s; }
  }
  if (lane == 0) wsum[wid] = ssq;
  __syncthreads();
  if (tid == 0) vpart[blockIdx.x] = (wsum[0] + wsum[1]) + (wsum[2] + wsum[3]);
}

// t[j] = sum_i v_un[i]*W[i][j]; tpart[bid] = sum_j t[j]^2 over this block's cols
__global__ void __launch_bounds__(256)
t_kernel(const float* __restrict__ W, const float* __restrict__ v_un,
         float* __restrict__ tpart)
{
  __shared__ float red[256];
  const int tid = threadIdx.x;
  const int j = (int)blockIdx.x * 256 + tid;
  float a0 = 0.f, a1 = 0.f, a2 = 0.f, a3 = 0.f;
  for (int i = 0; i < DDIM; i += 4) {
    a0 += v_un[i + 0] * W[(size_t)(i + 0) * DDIM + j];
    a1 += v_un[i + 1] * W[(size_t)(i + 1) * DDIM + j];
    a2 += v_un[i + 2] * W[(size_t)(i + 2) * DDIM + j];
    a3 += v_un[i + 3] * W[(size_t)(i + 3) * DDIM + j];
  }
  float t = (a0 + a1) + (a2 + a3);
  red[tid] = t * t;
  __syncthreads();
  for (int s = 128; s > 0; s >>= 1) {
    if (tid < s) red[tid] += red[tid + s];
    __syncthreads();
  }
  if (tid == 0) tpart[blockIdx.x] = red[0];
}

__global__ void finalize_kernel(const float* __restrict__ vpart,
                                const float* __restrict__ tpart,
                                float* __restrict__ inv_out)
{
  float sv = 0.f, st = 0.f;
  for (int i = 0; i < 64; ++i) sv += vpart[i];
  for (int i = 0; i < 4; ++i) st += tpart[i];
  float sigma = sqrtf(st / sv);
  inv_out[0] = (sigma > 0.9f) ? (0.9f / sigma) : 1.0f;
}

__global__ void __launch_bounds__(256)
conv_bf16(const float* __restrict__ x, unsigned short* __restrict__ xb)
{
  const long long n = (long long)BROWS * DDIM;
  long long idx = ((long long)blockIdx.x * 256 + threadIdx.x) * 8;
  const long long stride = (long long)gridDim.x * 256 * 8;
  for (; idx < n; idx += stride) {
    float4 a = *(const float4*)(x + idx);
    float4 b = *(const float4*)(x + idx + 4);
    short8 t;
    t[0] = (short)f2bf(a.x); t[1] = (short)f2bf(a.y);
    t[2] = (short)f2bf(a.z); t[3] = (short)f2bf(a.w);
    t[4] = (short)f2bf(b.x); t[5] = (short)f2bf(b.y);
    t[6] = (short)f2bf(b.z); t[7] = (short)f2bf(b.w);
    *(short8*)(xb + idx) = t;
  }
}

extern "C" void kernel_launch(void* const* d_in, const int* in_sizes, int n_in,
                              void* d_out, int out_size, void* d_ws, size_t ws_size,
                              hipStream_t stream)
{
  const float* x  = (const float*)d_in[0];
  const float* w  = (const float*)d_in[1];
  const float* b  = (const float*)d_in[2];
  const float* u0 = (const float*)d_in[3];
  float* out = (float*)d_out;

  char* ws = (char*)d_ws;
  float* scal = (float*)ws;                    // [0..6]=maxabs chain, [8]=inv_factor,
                                               // [16..79]=vpart, [80..83]=tpart
  float* u_a  = (float*)(ws + 0x1000);
  float* u_b  = (float*)(ws + 0x2000);
  float* v_un = (float*)(ws + 0x3000);
  unsigned short* WT = (unsigned short*)(ws + 0x4000);
  unsigned short* P0 = (unsigned short*)(ws + 0x204000);
  unsigned short* P1 = (unsigned short*)(ws + 0x404000);
  unsigned short* xb = (unsigned short*)(ws + 0x604000);
  const size_t NEED_BIG = 0x604000ull + (size_t)BROWS * DDIM * 2;
  const bool big = (ws_size >= NEED_BIG);

  hipMemsetAsync(d_ws, 0, 4096, stream);
  hipLaunchKernelGGL(transpose_bf16, dim3(256), dim3(256), 0, stream, w, WT);
  if (big) hipLaunchKernelGGL(conv_bf16, dim3(2048), dim3(256), 0, stream, x, xb);

  // M = W^T W  (A=WT, Bt=WT), store bf16 + maxabs -> scal[0]
  hipLaunchKernelGGL((gemm_bt<1, 0>), dim3(64), dim3(256), 0, stream,
                     (const void*)WT, WT, (void*)P0,
                     (const float*)nullptr, &scal[0],
                     (const float*)nullptr, (const float*)nullptr);
  // u_a = u0 * M
  hipLaunchKernelGGL(gemv_pow, dim3(64), dim3(256), 0, stream, P0, u0, u_a);
  // M^2
  hipLaunchKernelGGL((gemm_bt<1, 0>), dim3(64), dim3(256), 0, stream,
                     (const void*)P0, P0, (void*)P1, &scal[0], &scal[1],
                     (const float*)nullptr, (const float*)nullptr);
  // u_b = u_a * M^2  (= u0 M^3)
  hipLaunchKernelGGL(gemv_pow, dim3(64), dim3(256), 0, stream, P1, u_a, u_b);
  // M^4
  hipLaunchKernelGGL((gemm_bt<1, 0>), dim3(64), dim3(256), 0, stream,
                     (const void*)P1, P1, (void*)P0, &scal[1], &scal[2],
                     (const float*)nullptr, (const float*)nullptr);
  // M^8
  hipLaunchKernelGGL((gemm_bt<1, 0>), dim3(64), dim3(256), 0, stream,
                     (const void*)P0, P0, (void*)P1, &scal[2], &scal[3],
                     (const float*)nullptr, (const float*)nullptr);
  // M^16
  hipLaunchKernelGGL((gemm_bt<1, 0>), dim3(64), dim3(256), 0, stream,
                     (const void*)P1, P1, (void*)P0, &scal[3], &scal[4],
                     (const float*)nullptr, (const float*)nullptr);
  // M^32
  hipLaunchKernelGGL((gemm_bt<1, 0>), dim3(64), dim3(256), 0, stream,
                     (const void*)P0, P0, (void*)P1, &scal[4], &scal[5],
                     (const float*)nullptr, (const float*)nullptr);
  // u_a = u_b * M^32  (= u0 M^35)
  hipLaunchKernelGGL(gemv_pow, dim3(64), dim3(256), 0, stream, P1, u_b, u_a);
  // M^64
  hipLaunchKernelGGL((gemm_bt<1, 0>), dim3(64), dim3(256), 0, stream,
                     (const void*)P1, P1, (void*)P0, &scal[5], &scal[6],
                     (const float*)nullptr, (const float*)nullptr);
  // u_b = u_a * M^64  (= u0 M^99 direction)
  hipLaunchKernelGGL(gemv_pow, dim3(64), dim3(256), 0, stream, P0, u_a, u_b);

  // v_un = d99 * W^T (rows of W), ssq partials
  hipLaunchKernelGGL(v_kernel, dim3(64), dim3(256), 0, stream, w, u_b, v_un, &scal[16]);
  // t = v_un * W, ssq partials
  hipLaunchKernelGGL(t_kernel, dim3(4), dim3(256), 0, stream, w, v_un, &scal[80]);
  // sigma = sqrt(ssq_t/ssq_v); inv = min(1, 0.9/sigma)
  hipLaunchKernelGGL(finalize_kernel, dim3(1), dim3(1), 0, stream,
                     &scal[16], &scal[80], &scal[8]);

  // out = (x @ W) * inv + b
  if (big) {
    hipLaunchKernelGGL((gemm_bt<1, 1>), dim3(2048), dim3(256), 0, stream,
                       (const void*)xb, WT, (void*)out,
                       (const float*)nullptr, (float*)nullptr, &scal[8], b);
  } else {
    hipLaunchKernelGGL((gemm_bt<0, 1>), dim3(2048), dim3(256), 0, stream,
                       (const void*)x, WT, (void*)out,
                       (const float*)nullptr, (float*)nullptr, &scal[8], b);
  }
}

// Round 2
// 326.071 us; speedup vs baseline: 1.0754x; 1.0754x over previous
//
#include <hip/hip_runtime.h>
#include <hip/hip_bf16.h>
#include <cstdint>
#include <cstddef>

#define DDIM 1024
#define BROWS 32768

typedef __attribute__((ext_vector_type(8))) short short8;
typedef __attribute__((ext_vector_type(4))) float floatx4;

__device__ __forceinline__ float bf2f(unsigned short u) {
  return __uint_as_float(((unsigned int)u) << 16);
}
__device__ __forceinline__ unsigned short f2bf(float f) {
  unsigned int u = __float_as_uint(f);
  u += 0x7FFFu + ((u >> 16) & 1u);
  return (unsigned short)(u >> 16);
}

__device__ __forceinline__ void load_lds16(const void* g, void* l) {
  __builtin_amdgcn_global_load_lds(
      (const __attribute__((address_space(1))) unsigned int*)g,
      (__attribute__((address_space(3))) unsigned int*)l,
      16, 0, 0);
}

// ---------------------------------------------------------------------------
// Big GEMM: Out[i][j] = (sum_k Af[i][k]*bf16(Bt[j][k])) * inv + bias[j]
// A is f32 (x), reg-staged + converted to bf16 in LDS. 128x128 tile, BK=32.
// XCD-swizzled block mapping; LDS-staged epilogue for full-line f32 stores.
// ---------------------------------------------------------------------------
__global__ void __launch_bounds__(256, 2)
big_gemm(const float* __restrict__ Af, const unsigned short* __restrict__ Bt,
         float* __restrict__ Outf, const float* __restrict__ inv_ptr,
         const float* __restrict__ bias)
{
  __shared__ __align__(16) char smem[16896];
  unsigned short* As = (unsigned short*)smem;          // 8 KB
  unsigned short* Bs = (unsigned short*)(smem + 8192); // 8 KB
  float* epi = (float*)smem;                            // 16.5 KB (reuse, stride 132)

  const int tid  = threadIdx.x;
  const int lane = tid & 63;
  const int wid  = tid >> 6;
  const int wr = wid >> 1, wc = wid & 1;
  const int g = lane >> 4, r = lane & 15;

  // XCD-aware swizzle: 2048 blocks, 8 XCDs -> each XCD gets a contiguous
  // range of 256 tiles = 32 m-panels x 8 n-tiles (A-panel reuse in its L2).
  const int swz = (int)((blockIdx.x & 7) * 256 + (blockIdx.x >> 3));
  const int bn0 = (swz & 7) * 128;
  const int bm0 = (swz >> 3) * 128;

  const floatx4 zero4 = {0.f, 0.f, 0.f, 0.f};
  floatx4 acc[4][4];
#pragma unroll
  for (int m = 0; m < 4; ++m)
#pragma unroll
    for (int n = 0; n < 4; ++n) acc[m][n] = zero4;

  for (int kk = 0; kk < DDIM; kk += 32) {
    __syncthreads();
    // stage B tile (bf16, async direct-to-LDS)
#pragma unroll
    for (int p = 0; p < 2; ++p) {
      const int o = p * 4096 + tid * 16;  // byte offset in tile
      const int row = o >> 6;             // 64B per row (32 bf16)
      const int cole = (o & 63) >> 1;     // element col (0,8,16,24)
      load_lds16(Bt + (size_t)(bn0 + row) * DDIM + kk + cole, (char*)Bs + o);
    }
    // stage A tile: f32 -> bf16 reg-convert
#pragma unroll
    for (int p = 0; p < 2; ++p) {
      const int o = p * 4096 + tid * 16;
      const int row = o >> 6;
      const int cole = (o & 63) >> 1;
      const float4* s = (const float4*)(Af + (size_t)(bm0 + row) * DDIM + kk + cole);
      float4 x0 = s[0], x1 = s[1];
      short8 t;
      t[0] = (short)f2bf(x0.x); t[1] = (short)f2bf(x0.y);
      t[2] = (short)f2bf(x0.z); t[3] = (short)f2bf(x0.w);
      t[4] = (short)f2bf(x1.x); t[5] = (short)f2bf(x1.y);
      t[6] = (short)f2bf(x1.z); t[7] = (short)f2bf(x1.w);
      *(short8*)((char*)As + o) = t;
    }
    __syncthreads();

    short8 afr[4], bfr[4];
#pragma unroll
    for (int m = 0; m < 4; ++m)
      afr[m] = *(const short8*)((const char*)As + (wr * 64 + m * 16 + r) * 64 + g * 16);
#pragma unroll
    for (int n = 0; n < 4; ++n)
      bfr[n] = *(const short8*)((const char*)Bs + (wc * 64 + n * 16 + r) * 64 + g * 16);
#pragma unroll
    for (int m = 0; m < 4; ++m)
#pragma unroll
      for (int n = 0; n < 4; ++n)
        acc[m][n] = __builtin_amdgcn_mfma_f32_16x16x32_bf16(afr[m], bfr[n], acc[m][n], 0, 0, 0);
  }

  // Epilogue: stage 32x128 f32 chunks in LDS, store 64B/thread contiguous.
  const float inv = *inv_ptr;
  float bv[4];
#pragma unroll
  for (int n = 0; n < 4; ++n) bv[n] = bias[bn0 + wc * 64 + n * 16 + r];

#pragma unroll
  for (int m = 0; m < 4; ++m) {
    __syncthreads();  // LDS free (frags read / previous chunk stored)
#pragma unroll
    for (int n = 0; n < 4; ++n)
#pragma unroll
      for (int q = 0; q < 4; ++q)
        epi[(wr * 16 + g * 4 + q) * 132 + wc * 64 + n * 16 + r] =
            acc[m][n][q] * inv + bv[n];
    __syncthreads();
    const int lrow = tid >> 3;            // 0..31
    const int lc0  = (tid & 7) * 16;      // 16 floats per thread
    const int grow = bm0 + m * 16 + (lrow & 15) + (lrow >> 4) * 64;
    float4* dst = (float4*)(Outf + (size_t)grow * DDIM + bn0 + lc0);
    const float4* sv = (const float4*)(epi + lrow * 132 + lc0);
    dst[0] = sv[0]; dst[1] = sv[1]; dst[2] = sv[2]; dst[3] = sv[3];
  }
}

// ---------------------------------------------------------------------------
// Small square GEMM (1024^3): C[i][j] = sum_k A[i][k]*Bt[j][k], bf16 in/out.
// 32x32 tiles -> 1024 blocks (4/CU), BK=64, double-buffered global_load_lds
// (stage-next-before-compute), XOR-swizzled LDS (read-side swizzle matched by
// pre-swizzled global source chunks; LDS dest stays linear for gload_lds).
// Output scaled by c^2 (c = 2^-e from in_max, exact) + atomicMax |out|.
// ---------------------------------------------------------------------------
__global__ void __launch_bounds__(256, 4)
sq_gemm(const unsigned short* __restrict__ A, const unsigned short* __restrict__ Bt,
        unsigned short* __restrict__ Out, const float* __restrict__ in_max,
        float* __restrict__ out_max)
{
  __shared__ __align__(16) unsigned short As[2][2048]; // 2 x 4KB: [32][64]
  __shared__ __align__(16) unsigned short Bs[2][2048];
  __shared__ float redw[4];

  const int tid  = threadIdx.x;
  const int lane = tid & 63;
  const int wid  = tid >> 6;
  const int wr = wid >> 1, wc = wid & 1;
  const int g = lane >> 4, r = lane & 15;

  const int bm0 = (int)(blockIdx.x >> 5) * 32;
  const int bn0 = (int)(blockIdx.x & 31) * 32;

  // staging: thread covers LDS bytes [tid*16, tid*16+16)
  const int so   = tid * 16;
  const int srow = so >> 7;            // 128B per row (64 bf16)
  const int sc16 = (so >> 4) & 7;      // 16B chunk in row
  const int scs  = sc16 ^ (srow & 7);  // pre-swizzled source chunk
  const unsigned short* aSrc = A  + (size_t)(bm0 + srow) * DDIM + scs * 8;
  const unsigned short* bSrc = Bt + (size_t)(bn0 + srow) * DDIM + scs * 8;

  floatx4 acc = {0.f, 0.f, 0.f, 0.f};

  // prologue: stage K-tile 0 into buf 0
  load_lds16(aSrc, (char*)&As[0][0] + so);
  load_lds16(bSrc, (char*)&Bs[0][0] + so);
  __syncthreads();

  const int arow = wr * 16 + r;
  const int brow = wc * 16 + r;
  int buf = 0;
  for (int t = 0; t < 16; ++t) {
    if (t + 1 < 16) {
      const int kk = (t + 1) * 64;
      load_lds16(aSrc + kk, (char*)&As[buf ^ 1][0] + so);
      load_lds16(bSrc + kk, (char*)&Bs[buf ^ 1][0] + so);
    }
#pragma unroll
    for (int ks = 0; ks < 2; ++ks) {
      const int chunk = ((ks << 2) + g) ^ (r & 7);
      short8 af = *(const short8*)((const char*)&As[buf][0] + (arow << 7) + (chunk << 4));
      short8 bf = *(const short8*)((const char*)&Bs[buf][0] + (brow << 7) + (chunk << 4));
      acc = __builtin_amdgcn_mfma_f32_16x16x32_bf16(af, bf, acc, 0, 0, 0);
    }
    __syncthreads();  // drains vmcnt (next buf staged) + lgkm
    buf ^= 1;
  }

  float c = 1.0f;
  if (in_max != nullptr) {
    int e;
    (void)frexpf(*in_max, &e);
    c = ldexpf(1.0f, -e);  // power of two: c*max in [0.5,1)
  }
  const float c2 = c * c;
  float lmax = 0.0f;
  const int ocol = bn0 + wc * 16 + r;
#pragma unroll
  for (int q = 0; q < 4; ++q) {
    const int orow = bm0 + wr * 16 + g * 4 + q;
    float v = acc[q] * c2;
    Out[(size_t)orow * DDIM + ocol] = f2bf(v);
    lmax = fmaxf(lmax, fabsf(v));
  }
#pragma unroll
  for (int off = 32; off > 0; off >>= 1) lmax = fmaxf(lmax, __shfl_down(lmax, off));
  if (lane == 0) redw[wid] = lmax;
  __syncthreads();
  if (tid == 0) {
    float m = fmaxf(fmaxf(redw[0], redw[1]), fmaxf(redw[2], redw[3]));
    atomicMax((unsigned int*)out_max, __float_as_uint(m));
  }
}

// WT[n][k] = bf16(W[k][n])
__global__ void __launch_bounds__(256)
transpose_bf16(const float* __restrict__ W, unsigned short* __restrict__ WT)
{
  __shared__ float tile[64][65];
  const int bx = blockIdx.x & 15;   // k tile
  const int by = blockIdx.x >> 4;   // n tile
  const int tid = threadIdx.x;
  const int c = tid & 63;
  const int r0 = tid >> 6;
#pragma unroll
  for (int p = 0; p < 16; ++p) {
    int kr = p * 4 + r0;
    tile[kr][c] = W[(size_t)(bx * 64 + kr) * DDIM + by * 64 + c];
  }
  __syncthreads();
#pragma unroll
  for (int p = 0; p < 16; ++p) {
    int nr = p * 4 + r0;
    WT[(size_t)(by * 64 + nr) * DDIM + bx * 64 + c] = f2bf(tile[c][nr]);
  }
}

// vout[j] = 2^-12 * sum_i vin[i] * P[j][i]   (P symmetric bf16 1024x1024)
__global__ void __launch_bounds__(256)
gemv_pow(const unsigned short* __restrict__ P, const float* __restrict__ vin,
         float* __restrict__ vout)
{
  const int tid = threadIdx.x;
  const int lane = tid & 63;
  const int wid = tid >> 6;
  float vs[16];
  const float4* vv = (const float4*)(vin + lane * 16);
#pragma unroll
  for (int i = 0; i < 4; ++i) {
    float4 t = vv[i];
    vs[i * 4 + 0] = t.x; vs[i * 4 + 1] = t.y; vs[i * 4 + 2] = t.z; vs[i * 4 + 3] = t.w;
  }
#pragma unroll
  for (int rr = 0; rr < 4; ++rr) {
    const int row = (int)blockIdx.x * 16 + wid * 4 + rr;
    const unsigned short* pr = P + (size_t)row * DDIM + lane * 16;
    short8 p0 = *(const short8*)pr;
    short8 p1 = *(const short8*)(pr + 8);
    float s = 0.f;
#pragma unroll
    for (int e = 0; e < 8; ++e) s += bf2f((unsigned short)p0[e]) * vs[e];
#pragma unroll
    for (int e = 0; e < 8; ++e) s += bf2f((unsigned short)p1[e]) * vs[8 + e];
#pragma unroll
    for (int off = 32; off > 0; off >>= 1) s += __shfl_down(s, off);
    if (lane == 0) vout[row] = s * 0x1p-12f;
  }
}

// v_un[i] = sum_j d[j] * W[i][j]; per-block ssq partial -> vpart[bid]
__global__ void __launch_bounds__(256)
v_kernel(const float* __restrict__ W, const float* __restrict__ d,
         float* __restrict__ v_un, float* __restrict__ vpart)
{
  __shared__ float wsum[4];
  const int tid = threadIdx.x;
  const int lane = tid & 63;
  const int wid = tid >> 6;
  float vs[16];
  const float4* dv = (const float4*)(d + lane * 16);
#pragma unroll
  for (int i = 0; i < 4; ++i) {
    float4 t = dv[i];
    vs[i * 4 + 0] = t.x; vs[i * 4 + 1] = t.y; vs[i * 4 + 2] = t.z; vs[i * 4 + 3] = t.w;
  }
  float ssq = 0.f;
#pragma unroll
  for (int rr = 0; rr < 4; ++rr) {
    const int row = (int)blockIdx.x * 16 + wid * 4 + rr;
    const float4* wrow = (const float4*)(W + (size_t)row * DDIM + lane * 16);
    float s = 0.f;
#pragma unroll
    for (int i = 0; i < 4; ++i) {
      float4 t = wrow[i];
      s += t.x * vs[i * 4 + 0] + t.y * vs[i * 4 + 1] + t.z * vs[i * 4 + 2] + t.w * vs[i * 4 + 3];
    }
#pragma unroll
    for (int off = 32; off > 0; off >>= 1) s += __shfl_down(s, off);
    if (lane == 0) { v_un[row] = s; ssq += s * s; }
  }
  if (lane == 0) wsum[wid] = ssq;
  __syncthreads();
  if (tid == 0) vpart[blockIdx.x] = (wsum[0] + wsum[1]) + (wsum[2] + wsum[3]);
}

// t[j] = sum_i v_un[i]*W[i][j]; tpart[bid] = sum over this block's 32 cols of t^2
__global__ void __launch_bounds__(256)
t_kernel(const float* __restrict__ W, const float* __restrict__ v_un,
         float* __restrict__ tpart)
{
  __shared__ float part[8][33];
  const int tid = threadIdx.x;
  const int col = (int)blockIdx.x * 32 + (tid & 31);
  const int ch = tid >> 5;  // 0..7 i-chunks of 128
  float s = 0.f;
  const int i0 = ch * 128;
  for (int i = i0; i < i0 + 128; ++i)
    s += v_un[i] * W[(size_t)i * DDIM + col];
  part[ch][tid & 31] = s;
  __syncthreads();
  if (tid < 32) {
    float t = 0.f;
#pragma unroll
    for (int c2 = 0; c2 < 8; ++c2) t += part[c2][tid];
    part[0][tid] = t * t;
  }
  __syncthreads();
  if (tid == 0) {
    float ss = 0.f;
#pragma unroll
    for (int c = 0; c < 32; ++c) ss += part[0][c];
    tpart[blockIdx.x] = ss;
  }
}

__global__ void finalize_kernel(const float* __restrict__ vpart,
                                const float* __restrict__ tpart,
                                float* __restrict__ inv_out)
{
  float sv = 0.f, st = 0.f;
  for (int i = 0; i < 64; ++i) sv += vpart[i];
  for (int i = 0; i < 32; ++i) st += tpart[i];
  float sigma = sqrtf(st / sv);
  inv_out[0] = (sigma > 0.9f) ? (0.9f / sigma) : 1.0f;
}

extern "C" void kernel_launch(void* const* d_in, const int* in_sizes, int n_in,
                              void* d_out, int out_size, void* d_ws, size_t ws_size,
                              hipStream_t stream)
{
  const float* x  = (const float*)d_in[0];
  const float* w  = (const float*)d_in[1];
  const float* b  = (const float*)d_in[2];
  const float* u0 = (const float*)d_in[3];
  float* out = (float*)d_out;

  char* ws = (char*)d_ws;
  float* scal = (float*)ws;  // [0..6]=maxabs chain, [8]=inv, [16..79]=vpart, [80..111]=tpart
  float* u_a  = (float*)(ws + 0x1000);
  float* u_b  = (float*)(ws + 0x2000);
  float* v_un = (float*)(ws + 0x3000);
  unsigned short* WT = (unsigned short*)(ws + 0x4000);
  unsigned short* P0 = (unsigned short*)(ws + 0x204000);
  unsigned short* P1 = (unsigned short*)(ws + 0x404000);

  hipMemsetAsync(d_ws, 0, 4096, stream);
  hipLaunchKernelGGL(transpose_bf16, dim3(256), dim3(256), 0, stream, w, WT);

  // M = W^T W
  hipLaunchKernelGGL(sq_gemm, dim3(1024), dim3(256), 0, stream,
                     WT, WT, P0, (const float*)nullptr, &scal[0]);
  hipLaunchKernelGGL(gemv_pow, dim3(64), dim3(256), 0, stream, P0, u0, u_a);   // u0 M
  hipLaunchKernelGGL(sq_gemm, dim3(1024), dim3(256), 0, stream,
                     P0, P0, P1, &scal[0], &scal[1]);                          // M^2
  hipLaunchKernelGGL(gemv_pow, dim3(64), dim3(256), 0, stream, P1, u_a, u_b);  // u0 M^3
  hipLaunchKernelGGL(sq_gemm, dim3(1024), dim3(256), 0, stream,
                     P1, P1, P0, &scal[1], &scal[2]);                          // M^4
  hipLaunchKernelGGL(sq_gemm, dim3(1024), dim3(256), 0, stream,
                     P0, P0, P1, &scal[2], &scal[3]);                          // M^8
  hipLaunchKernelGGL(sq_gemm, dim3(1024), dim3(256), 0, stream,
                     P1, P1, P0, &scal[3], &scal[4]);                          // M^16
  hipLaunchKernelGGL(sq_gemm, dim3(1024), dim3(256), 0, stream,
                     P0, P0, P1, &scal[4], &scal[5]);                          // M^32
  hipLaunchKernelGGL(gemv_pow, dim3(64), dim3(256), 0, stream, P1, u_b, u_a);  // u0 M^35
  hipLaunchKernelGGL(sq_gemm, dim3(1024), dim3(256), 0, stream,
                     P1, P1, P0, &scal[5], &scal[6]);                          // M^64
  hipLaunchKernelGGL(gemv_pow, dim3(64), dim3(256), 0, stream, P0, u_a, u_b);  // u0 M^99

  hipLaunchKernelGGL(v_kernel, dim3(64), dim3(256), 0, stream, w, u_b, v_un, &scal[16]);
  hipLaunchKernelGGL(t_kernel, dim3(32), dim3(256), 0, stream, w, v_un, &scal[80]);
  hipLaunchKernelGGL(finalize_kernel, dim3(1), dim3(1), 0, stream,
                     &scal[16], &scal[80], &scal[8]);

  // out = (x @ W) * inv + b
  hipLaunchKernelGGL(big_gemm, dim3(2048), dim3(256), 0, stream,
                     x, WT, out, &scal[8], b);
}